// Round 10
// baseline (8011.019 us; speedup 1.0000x reference)
//
#include <hip/hip_runtime.h>
#include <hip/hip_bf16.h>

typedef _Float16 half8 __attribute__((ext_vector_type(8)));
typedef _Float16 half4v __attribute__((ext_vector_type(4)));
typedef float f32x4 __attribute__((ext_vector_type(4)));

#define BB 64
#define SS 512
#define HH 1024
#define G4 4096
#define SLOT 65536  // elements per 64x1024 fp16 h-slot

// STAGGER barrier layout (dword indices, 64B spacing):
//   arr[s][g] at 16*(s*8+g)   (s=k&7 slot, g=block group, 32 blocks each)
//   glb[s]    at 1024 + 16*s
//   go[g]     at 1280 + 16*g
#define ARW(s, g) (16 * ((s) * 8 + (g)))
#define GLBW(s) (1024 + 16 * (s))
#define GOW(g) (1280 + 16 * (g))
// SAFE-mode (R5 fallback) barrier words
#define SB_ARR(g) ((g) * 32)
#define SB_GLB 256
#define SB_GO(g) (288 + (g) * 32)

__device__ __forceinline__ float sigmf(float x) { return 1.0f / (1.0f + __expf(-x)); }
__device__ __forceinline__ float tanhfast(float x) { return 2.0f / (1.0f + __expf(-2.0f * x)) - 1.0f; }

__device__ __forceinline__ unsigned aload(const unsigned* p) {
  return __hip_atomic_load(p, __ATOMIC_RELAXED, __HIP_MEMORY_SCOPE_AGENT);
}
__device__ __forceinline__ void wait_ge(const unsigned* p, unsigned tgt) {
  while (aload(p) < tgt) __builtin_amdgcn_s_sleep(1);
}
__device__ __forceinline__ unsigned aadd(unsigned* p) {
  return __hip_atomic_fetch_add(p, 1u, __ATOMIC_RELAXED, __HIP_MEMORY_SCOPE_AGENT);
}
__device__ __forceinline__ void astore(unsigned* p, unsigned v) {
  __hip_atomic_store(p, v, __ATOMIC_RELAXED, __HIP_MEMORY_SCOPE_AGENT);
}
__device__ __forceinline__ void amax(unsigned* p, unsigned v) {
  __hip_atomic_fetch_max(p, v, __ATOMIC_RELAXED, __HIP_MEMORY_SCOPE_AGENT);
}

// inputs[b][s][h] (f32) -> x16[s][b][h] (fp16), time-major
__global__ __launch_bounds__(256) void convert_x_kernel(const float* __restrict__ in,
                                                        _Float16* __restrict__ x16) {
  size_t idx = (size_t)blockIdx.x * 256 + threadIdx.x;
  int h4 = (int)(idx & 255);
  int s  = (int)((idx >> 8) & 511);
  int b  = (int)(idx >> 17);
  const float4* src = (const float4*)in;
  float4 v = src[((size_t)b * SS + s) * 256 + h4];
  half4v hv = { (_Float16)v.x, (_Float16)v.y, (_Float16)v.z, (_Float16)v.w };
  *(half4v*)(x16 + ((size_t)s * BB + b) * HH + (size_t)h4 * 4) = hv;
}

// W[l][k][n] (f32) -> wT[m][n][k] (fp16); m: 0=Wx l0, 1=Wx l1, 2=Wh l0, 3=Wh l1
__global__ __launch_bounds__(256) void convert_w_kernel(const float* __restrict__ Wx,
                                                        const float* __restrict__ Wh,
                                                        _Float16* __restrict__ wT) {
  __shared__ float tile[32][33];
  int m = blockIdx.x >> 12;
  int t = blockIdx.x & 4095;
  int tn = t & 127, tk = t >> 7;
  int l = m & 1, which = m >> 1;
  const float* src = (which ? Wh : Wx) + (size_t)l * HH * G4;
  int tx = threadIdx.x & 31, ty = threadIdx.x >> 5;
#pragma unroll
  for (int p = 0; p < 4; ++p) {
    int k = tk * 32 + ty + 8 * p, n = tn * 32 + tx;
    tile[ty + 8 * p][tx] = src[(size_t)k * G4 + n];
  }
  __syncthreads();
  _Float16* dst = wT + (size_t)m * G4 * HH;
#pragma unroll
  for (int p = 0; p < 4; ++p) {
    int n = tn * 32 + ty + 8 * p, k = tk * 32 + tx;
    dst[(size_t)n * HH + k] = (_Float16)tile[tx][ty + 8 * p];
  }
}

// One staggered interval (G = compile-time group 0..3). Single prefetch buffer
// pA/pR: consumed by MFMA at interval start, refilled immediately after (next
// interval's data; WAR handled by compiler ordering). Two light barriers:
// raw s_barrier at top (vmem stays in flight), lgkmcnt-only barrier mid.
#define STEP(G)                                                                        \
  {                                                                                    \
    const int k = 4 * m + (G);                                                         \
    if (tid == 0 && k >= 3) wait_ge(bar + GOW(grp), (unsigned)(k - 2));                \
    __builtin_amdgcn_s_barrier();                                                      \
    asm volatile("" ::: "memory");                                                     \
    const bool act = layer ? (m >= 1) : (m < SS);                                      \
    f32x4 acc0 = {0.f, 0.f, 0.f, 0.f};                                                 \
    f32x4 acc1 = {0.f, 0.f, 0.f, 0.f};                                                 \
    if (act) {                                                                         \
      _Pragma("unroll") for (int kk = 0; kk < 4; ++kk) {                               \
        acc0 = __builtin_amdgcn_mfma_f32_16x16x32_f16(pA[kk], Be[kk * 2 + 0], acc0, 0, 0, 0); \
        acc1 = __builtin_amdgcn_mfma_f32_16x16x32_f16(pA[kk], Be[kk * 2 + 1], acc1, 0, 0, 0); \
      }                                                                                \
      _Pragma("unroll") for (int kk = 0; kk < 4; ++kk) {                               \
        acc0 = __builtin_amdgcn_mfma_f32_16x16x32_f16(pR[kk], Br[kk * 2 + 0], acc0, 0, 0, 0); \
        acc1 = __builtin_amdgcn_mfma_f32_16x16x32_f16(pR[kk], Br[kk * 2 + 1], acc1, 0, 0, 0); \
      }                                                                                \
    }                                                                                  \
    { /* prefetch interval k+1 inputs (source published at k-3; gate covers it) */     \
      const int gn = ((G) + 1) & 3;                                                    \
      const int mn = ((G) == 3) ? m + 1 : m;                                           \
      if (layer == 0) {                                                                \
        if (mn < SS) {                                                                 \
          const _Float16* pa = x16 + (size_t)mn * SLOT + (size_t)(16 * gn + l15) * HH + kbase + 8 * lg;   \
          const _Float16* pr = h1buf + (size_t)mn * SLOT + (size_t)(16 * gn + l15) * HH + kbase + 8 * lg; \
          _Pragma("unroll") for (int kk = 0; kk < 4; ++kk) {                           \
            pA[kk] = *(const half8*)(pa + 32 * kk);                                    \
            pR[kk] = *(const half8*)(pr + 32 * kk);                                    \
          }                                                                            \
        }                                                                              \
      } else {                                                                         \
        if (mn >= 1 && mn <= SS) {                                                     \
          const _Float16* pa = h1buf + (size_t)mn * SLOT + (size_t)(16 * gn + l15) * HH + kbase + 8 * lg;       \
          const _Float16* pr = h2buf + (size_t)(mn - 1) * SLOT + (size_t)(16 * gn + l15) * HH + kbase + 8 * lg; \
          _Pragma("unroll") for (int kk = 0; kk < 4; ++kk) {                           \
            pA[kk] = *(const half8*)(pa + 32 * kk);                                    \
            pR[kk] = *(const half8*)(pr + 32 * kk);                                    \
          }                                                                            \
        }                                                                              \
      }                                                                                \
    }                                                                                  \
    if (act) {                                                                         \
      *(f32x4*)&part[w][l15][4 * lg] = acc0;                                           \
      *(f32x4*)&part[w][16 + l15][4 * lg] = acc1;                                      \
    }                                                                                  \
    asm volatile("s_waitcnt lgkmcnt(0)" ::: "memory"); /* LDS drain only */            \
    __builtin_amdgcn_s_barrier();                                                      \
    asm volatile("" ::: "memory");                                                     \
    if (act && tid < 64) { /* wave 0: gather + epilogue + publish */                   \
      float v[8];                                                                      \
      _Pragma("unroll") for (int qq = 0; qq < 8; ++qq) {                               \
        int q = (qq + 2 * m2) & 7; /* bank-conflict rotation: 2-way max */             \
        float s = 0.f;                                                                 \
        _Pragma("unroll") for (int ww = 0; ww < 8; ++ww)                               \
            s += part[ww][8 * m2 + q][er];                                             \
        v[q] = s + bs[q];                                                              \
      }                                                                                \
      float i0 = sigmf(v[0]), f0 = sigmf(v[1]), g0 = tanhfast(v[2]), o0 = sigmf(v[3]); \
      float i1 = sigmf(v[4]), f1 = sigmf(v[5]), g1 = tanhfast(v[6]), o1 = sigmf(v[7]); \
      float cn0 = f0 * cs0[(G)] + i0 * g0;                                             \
      float cn1 = f1 * cs1[(G)] + i1 * g1;                                             \
      cs0[(G)] = cn0; cs1[(G)] = cn1;                                                  \
      float h0 = tanhfast(cn0) * o0;                                                   \
      float h1 = tanhfast(cn1) * o1;                                                   \
      if (layer == 1) { hx0[(G)] = fmaxf(hx0[(G)], h0); hx1[(G)] = fmaxf(hx1[(G)], h1); } \
      _Float16* hout = (layer == 0) ? h1buf + (size_t)(m + 1) * SLOT                   \
                                    : h2buf + (size_t)m * SLOT;                        \
      int row = 16 * (G) + er;                                                         \
      unsigned pk = ((unsigned)__builtin_bit_cast(unsigned short, (_Float16)h1) << 16) | \
                    (unsigned)__builtin_bit_cast(unsigned short, (_Float16)h0);        \
      astore((unsigned*)hout + ((row * HH + hc0) >> 1), pk);                           \
      asm volatile("s_waitcnt vmcnt(0)" ::: "memory"); /* wave-0-local drain */        \
    }                                                                                  \
    if (tid == 0) { /* parallel arrive tree: 32 RMWs/line x 8 lines, then 8, fanout */ \
      unsigned s8 = (unsigned)(k & 7), r = (unsigned)(k >> 3);                         \
      unsigned prev = aadd(bar + ARW(s8, grp));                                        \
      if (prev == 32u * r + 31u) {                                                     \
        unsigned p2 = aadd(bar + GLBW(s8));                                            \
        if (p2 == 8u * r + 7u) {                                                       \
          _Pragma("unroll") for (int gg = 0; gg < 8; ++gg)                             \
              amax(bar + GOW(gg), (unsigned)(k + 1));                                  \
        }                                                                              \
      }                                                                                \
    }                                                                                  \
  }

// Batch-staggered persistent LSTM: 256 blocks x 512 threads, 1 block/CU.
// Blocks 0..127: layer1; 128..255: layer2. Batch in 4 groups x 16 rows;
// interval k=4m+g: L1 does group g step m, L2 does group g step m-1.
// Recurrence spans 4 intervals; wait at k requires release(k-3); prefetch at k
// touches data published at k-3 (exactly covered). Release chain must fit in
// ~3 intervals -> L reduction is the point of the new arrive tree.
__global__ __launch_bounds__(512, 2) void lstm_stagger(
    const _Float16* __restrict__ x16, const _Float16* __restrict__ wT,
    const float* __restrict__ bx, const float* __restrict__ bh,
    _Float16* __restrict__ h1buf, _Float16* __restrict__ h2buf,
    float* __restrict__ hmax, unsigned* __restrict__ bar) {
  __shared__ float part[8][32][20];  // [wave][col][row] = 20,480 B (16B-aligned cols)

  const int bid = blockIdx.x;        // 0..255
  const int layer = bid >> 7;
  const int j = bid & 127;           // h-cols [8j, 8j+8)
  const int grp = bid & 7;
  const int tid = threadIdx.x;
  const int w = tid >> 6, l = tid & 63;
  const int l15 = l & 15, lg = l >> 4;

  // one-time: weight fragments into registers (8 waves x K-slice 128)
  const _Float16* wTe = wT + (size_t)layer * G4 * HH;
  const _Float16* wTr = wT + (size_t)(2 + layer) * G4 * HH;
  const int kbase = w * 128;
  half8 Be[8], Br[8];
#pragma unroll
  for (int kk = 0; kk < 4; ++kk)
#pragma unroll
    for (int c = 0; c < 2; ++c) {
      int nl = 16 * c + l15;
      size_t gcol = (size_t)((nl & 3) * HH + 8 * j + (nl >> 2));
      Be[kk * 2 + c] = *(const half8*)(wTe + gcol * HH + kbase + 32 * kk + 8 * lg);
      Br[kk * 2 + c] = *(const half8*)(wTr + gcol * HH + kbase + 32 * kk + 8 * lg);
    }

  // epilogue state (wave-0 lanes: row er in group, cols hc0..hc0+1)
  const int er = tid >> 2, m2 = tid & 3;
  const int hc0 = 8 * j + 2 * m2;
  float bs[8];
#pragma unroll
  for (int dm = 0; dm < 2; ++dm)
#pragma unroll
    for (int g = 0; g < 4; ++g)
      bs[4 * dm + g] = bx[layer * G4 + g * HH + hc0 + dm] + bh[layer * G4 + g * HH + hc0 + dm];
  float cs0[4] = {0.f, 0.f, 0.f, 0.f}, cs1[4] = {0.f, 0.f, 0.f, 0.f};
  float hx0[4] = {-2.f, -2.f, -2.f, -2.f}, hx1[4] = {-2.f, -2.f, -2.f, -2.f};

  // single prefetch buffer; prologue loads interval-0 inputs (L1 only)
  half8 pA[4], pR[4];
  if (layer == 0) {
    const _Float16* pa = x16 + (size_t)l15 * HH + kbase + 8 * lg;
    const _Float16* pr = h1buf + (size_t)l15 * HH + kbase + 8 * lg;  // slot 0 = zeros
#pragma unroll
    for (int kk = 0; kk < 4; ++kk) {
      pA[kk] = *(const half8*)(pa + 32 * kk);
      pR[kk] = *(const half8*)(pr + 32 * kk);
    }
  }

#pragma unroll 1
  for (int m = 0; m <= SS; ++m) {
    STEP(0)
    STEP(1)
    STEP(2)
    STEP(3)
  }

  if (layer == 1 && tid < 64) {
#pragma unroll
    for (int g = 0; g < 4; ++g) {
      int row = 16 * g + er;
      hmax[row * HH + hc0]     = hx0[g];
      hmax[row * HH + hc0 + 1] = hx1[g];
    }
  }
}

// SAFE fallback (round-5 proven, 256 blocks, rings + per-step acquire fence).
__global__ __launch_bounds__(512, 2) void lstm_safe(
    const _Float16* __restrict__ x16, const _Float16* __restrict__ wT,
    const float* __restrict__ bx, const float* __restrict__ bh,
    _Float16* __restrict__ h1buf, _Float16* __restrict__ h2buf,
    float* __restrict__ hmax, unsigned* __restrict__ bar) {
  __shared__ float part[8][32][72];
  __shared__ float red[64][37];

  const int bid = blockIdx.x;
  const int layer = bid >> 7;
  const int j = bid & 127;
  const int tid = threadIdx.x;
  const int w = tid >> 6, l = tid & 63;
  const int l15 = l & 15, lg = l >> 4;
  const int grp = bid & 7;

  const _Float16* wTe = wT + (size_t)layer * G4 * HH;
  const _Float16* wTr = wT + (size_t)(2 + layer) * G4 * HH;
  const int kbase = w * 128;
  half8 Be[8], Br[8];
#pragma unroll
  for (int kk = 0; kk < 4; ++kk)
#pragma unroll
    for (int c = 0; c < 2; ++c) {
      int nl = 16 * c + l15;
      size_t gcol = (size_t)((nl & 3) * HH + 8 * j + (nl >> 2));
      Be[kk * 2 + c] = *(const half8*)(wTe + gcol * HH + kbase + 32 * kk + 8 * lg);
      Br[kk * 2 + c] = *(const half8*)(wTr + gcol * HH + kbase + 32 * kk + 8 * lg);
    }

  const int erow = tid >> 2, m2 = tid & 3;
  const int hc0 = 8 * j + 2 * m2;
  float bs[8];
  float c0 = 0.f, c1 = 0.f, hm0 = -2.f, hm1 = -2.f;
  if (tid < 256) {
#pragma unroll
    for (int dm = 0; dm < 2; ++dm)
#pragma unroll
      for (int g = 0; g < 4; ++g)
        bs[4 * dm + g] = bx[layer * G4 + g * HH + hc0 + dm] + bh[layer * G4 + g * HH + hc0 + dm];
  }

#pragma unroll 1
  for (int t = 0; t < SS + 2; ++t) {
    const bool act = (layer == 0) ? (t < SS) : (t >= 2);
    f32x4 acc[8];
#pragma unroll
    for (int i = 0; i < 8; ++i) acc[i] = (f32x4){0.f, 0.f, 0.f, 0.f};

    if (act) {
      const _Float16* Ae = (layer == 0) ? x16 + (size_t)t * SLOT
                                        : h1buf + (size_t)((t - 2) & 3) * SLOT;
      const _Float16* aep = Ae + (size_t)l15 * HH + kbase + 8 * lg;
      half8 a[16];
#pragma unroll
      for (int rf = 0; rf < 4; ++rf)
#pragma unroll
        for (int kk = 0; kk < 4; ++kk)
          a[rf * 4 + kk] = *(const half8*)(aep + (size_t)(16 * rf) * HH + 32 * kk);
#pragma unroll
      for (int rf = 0; rf < 4; ++rf)
#pragma unroll
        for (int kk = 0; kk < 4; ++kk) {
          acc[rf * 2 + 0] = __builtin_amdgcn_mfma_f32_16x16x32_f16(a[rf * 4 + kk], Be[kk * 2 + 0], acc[rf * 2 + 0], 0, 0, 0);
          acc[rf * 2 + 1] = __builtin_amdgcn_mfma_f32_16x16x32_f16(a[rf * 4 + kk], Be[kk * 2 + 1], acc[rf * 2 + 1], 0, 0, 0);
        }
    }

    if (tid == 0) {
      wait_ge(bar + SB_GO(grp), (unsigned)t);
      __builtin_amdgcn_fence(__ATOMIC_ACQUIRE, "agent");
    }
    __syncthreads();

    if (act) {
      const _Float16* Ah = (layer == 0) ? h1buf + (size_t)((t - 1) & 3) * SLOT
                                        : h2buf + (size_t)((t - 1) & 1) * SLOT;
      const _Float16* ahp = Ah + (size_t)l15 * HH + kbase + 8 * lg;
      half8 a[16];
#pragma unroll
      for (int rf = 0; rf < 4; ++rf)
#pragma unroll
        for (int kk = 0; kk < 4; ++kk)
          a[rf * 4 + kk] = *(const half8*)(ahp + (size_t)(16 * rf) * HH + 32 * kk);
#pragma unroll
      for (int rf = 0; rf < 4; ++rf)
#pragma unroll
        for (int kk = 0; kk < 4; ++kk) {
          acc[rf * 2 + 0] = __builtin_amdgcn_mfma_f32_16x16x32_f16(a[rf * 4 + kk], Br[kk * 2 + 0], acc[rf * 2 + 0], 0, 0, 0);
          acc[rf * 2 + 1] = __builtin_amdgcn_mfma_f32_16x16x32_f16(a[rf * 4 + kk], Br[kk * 2 + 1], acc[rf * 2 + 1], 0, 0, 0);
        }

#pragma unroll
      for (int rf = 0; rf < 4; ++rf)
#pragma unroll
        for (int c = 0; c < 2; ++c)
          *(f32x4*)&part[w][16 * c + l15][16 * rf + 4 * lg] = acc[rf * 2 + c];
      __syncthreads();

      {
        int col = tid >> 4, rq = tid & 15;
        f32x4 s = {0.f, 0.f, 0.f, 0.f};
#pragma unroll
        for (int ww = 0; ww < 8; ++ww)
          s += *(const f32x4*)&part[ww][col][4 * rq];
        red[4 * rq + 0][col] = s[0];
        red[4 * rq + 1][col] = s[1];
        red[4 * rq + 2][col] = s[2];
        red[4 * rq + 3][col] = s[3];
      }
      __syncthreads();

      if (tid < 256) {
        float v[8];
#pragma unroll
        for (int q = 0; q < 8; ++q) v[q] = red[erow][8 * m2 + q] + bs[q];
        float i0 = sigmf(v[0]), f0 = sigmf(v[1]), g0 = tanhfast(v[2]), o0 = sigmf(v[3]);
        float i1 = sigmf(v[4]), f1 = sigmf(v[5]), g1 = tanhfast(v[6]), o1 = sigmf(v[7]);
        c0 = f0 * c0 + i0 * g0;
        c1 = f1 * c1 + i1 * g1;
        float h0 = tanhfast(c0) * o0;
        float h1 = tanhfast(c1) * o1;
        if (layer == 1) { hm0 = fmaxf(hm0, h0); hm1 = fmaxf(hm1, h1); }
        _Float16* hout = (layer == 0) ? h1buf + (size_t)(t & 3) * SLOT
                                      : h2buf + (size_t)(t & 1) * SLOT;
        unsigned pk = ((unsigned)__builtin_bit_cast(unsigned short, (_Float16)h1) << 16) |
                      (unsigned)__builtin_bit_cast(unsigned short, (_Float16)h0);
        astore((unsigned*)hout + ((erow * HH + hc0) >> 1), pk);
      }
    }

    __syncthreads();
    if (tid == 0) {
      unsigned prev = aadd(bar + SB_ARR(grp));
      if (prev == 32u * (unsigned)(t + 1) - 1u) {
        unsigned p2 = aadd(bar + SB_GLB);
        if (p2 == 8u * (unsigned)(t + 1) - 1u) {
#pragma unroll
          for (int gg = 0; gg < 8; ++gg)
            astore(bar + SB_GO(gg), (unsigned)(t + 1));
        }
      }
    }
  }

  if (layer == 1 && tid < 256) {
    hmax[erow * HH + hc0]     = hm0;
    hmax[erow * HH + hc0 + 1] = hm1;
  }
}

__global__ __launch_bounds__(320) void classify_kernel(const float* __restrict__ hmax,
                                                       const float* __restrict__ Wp,
                                                       const float* __restrict__ bp,
                                                       float* __restrict__ out) {
  int tid = threadIdx.x;  // 320 = 64*5
  int b = tid / 5, jj = tid % 5;
  float s = bp[jj];
  const float* hp = hmax + (size_t)b * HH;
  for (int h = 0; h < HH; ++h) s = fmaf(hp[h], Wp[h * 5 + jj], s);
  out[tid] = s;
}

extern "C" void kernel_launch(void* const* d_in, const int* in_sizes, int n_in,
                              void* d_out, int out_size, void* d_ws, size_t ws_size,
                              hipStream_t stream) {
  const float* inputs = (const float*)d_in[0];
  const float* Wx = (const float*)d_in[1];
  const float* bx = (const float*)d_in[2];
  const float* Wh = (const float*)d_in[3];
  const float* bh = (const float*)d_in[4];
  const float* Wp = (const float*)d_in[5];
  const float* bp = (const float*)d_in[6];
  float* out = (float*)d_out;

  char* ws = (char*)d_ws;
  _Float16* x16 = (_Float16*)(ws + 0);          // 67,108,864
  _Float16* wT  = (_Float16*)(ws + 67108864);   // 33,554,432 -> 100,663,296

  const size_t TRAJ_BYTES = (size_t)513 * 131072;           // 67,239,936
  const size_t NEED_FAST = 100663296ull + 2 * TRAJ_BYTES + 262144 + 8192;  // 235,413,504
  bool fast = ws_size >= NEED_FAST;

  convert_x_kernel<<<32768, 256, 0, stream>>>(inputs, x16);
  convert_w_kernel<<<16384, 256, 0, stream>>>(Wx, Wh, wT);

  if (fast) {
    _Float16* h1traj = (_Float16*)(ws + 100663296);
    _Float16* h2traj = (_Float16*)(ws + 100663296 + TRAJ_BYTES);
    float* hmax = (float*)(ws + 100663296 + 2 * TRAJ_BYTES);
    unsigned* bar = (unsigned*)(ws + 100663296 + 2 * TRAJ_BYTES + 262144);
    hipMemsetAsync(h1traj, 0, 131072, stream);  // zero slot 0 (state at t = -1)
    hipMemsetAsync(h2traj, 0, 131072, stream);
    hipMemsetAsync(bar, 0, 8192, stream);
    lstm_stagger<<<256, 512, 0, stream>>>(x16, wT, bx, bh, h1traj, h2traj, hmax, bar);
    classify_kernel<<<1, 320, 0, stream>>>(hmax, Wp, bp, out);
  } else {
    _Float16* h1buf = (_Float16*)(ws + 100663296);          // 4 slots
    _Float16* h2buf = (_Float16*)(ws + 101187584);          // 2 slots
    float* hmax = (float*)(ws + 101449728);
    unsigned* bar = (unsigned*)(ws + 101711872);
    hipMemsetAsync(h1buf, 0, 524288, stream);
    hipMemsetAsync(h2buf, 0, 262144, stream);
    hipMemsetAsync(bar, 0, 8192, stream);
    lstm_safe<<<256, 512, 0, stream>>>(x16, wT, bx, bh, h1buf, h2buf, hmax, bar);
    classify_kernel<<<1, 320, 0, stream>>>(hmax, Wp, bp, out);
  }
}

// Round 12
// 6451.761 us; speedup vs baseline: 1.2417x; 1.2417x over previous
//
#include <hip/hip_runtime.h>
#include <hip/hip_bf16.h>

typedef _Float16 half8 __attribute__((ext_vector_type(8)));
typedef _Float16 half4v __attribute__((ext_vector_type(4)));
typedef float f32x4 __attribute__((ext_vector_type(4)));
typedef unsigned int u32;
typedef unsigned long long u64;

#define BB 64
#define SS 512
#define HH 1024
#define G4 4096
#define SLOT 65536   // elements per 64x1024 fp16 h-slot
#define NSTEP 514

// LEAN barrier layout (dword indices; 64B = 16 dwords spacing):
//   arr[L][i]  (L=0,1; i<16; 8 blocks/line)  : 16*(L*16+i)      -> 0..511
//   lvl2[L]                                   : 512 + 16*L
//   go[L][b]   (dedicated line per block)     : 1024 + 16*(L*256+b)
#define ARRD(L, i) (16 * ((L) * 16 + (i)))
#define LVL2D(L) (512 + 16 * (L))
#define GOD(L, b) (1024 + 16 * ((L) * 256 + (b)))
// SAFE-mode (R5 fallback) barrier words
#define SB_ARR(g) ((g) * 32)
#define SB_GLB 256
#define SB_GO(g) (288 + (g) * 32)

__device__ __forceinline__ float sigmf(float x) { return 1.0f / (1.0f + __expf(-x)); }
__device__ __forceinline__ float tanhfast(float x) { return 2.0f / (1.0f + __expf(-2.0f * x)) - 1.0f; }

__device__ __forceinline__ u32 aload(const u32* p) {
  return __hip_atomic_load(p, __ATOMIC_RELAXED, __HIP_MEMORY_SCOPE_AGENT);
}
__device__ __forceinline__ void wait_ge(const u32* p, u32 tgt) {
  while (aload(p) < tgt) __builtin_amdgcn_s_sleep(1);
}
__device__ __forceinline__ u32 aadd(u32* p) {
  return __hip_atomic_fetch_add(p, 1u, __ATOMIC_RELAXED, __HIP_MEMORY_SCOPE_AGENT);
}
__device__ __forceinline__ void astore(u32* p, u32 v) {
  __hip_atomic_store(p, v, __ATOMIC_RELAXED, __HIP_MEMORY_SCOPE_AGENT);
}
__device__ __forceinline__ void astore64(u64* p, u64 v) {
  __hip_atomic_store(p, v, __ATOMIC_RELAXED, __HIP_MEMORY_SCOPE_AGENT);
}

// inputs[b][s][h] (f32) -> x16[s][b][h] (fp16), time-major
__global__ __launch_bounds__(256) void convert_x_kernel(const float* __restrict__ in,
                                                        _Float16* __restrict__ x16) {
  size_t idx = (size_t)blockIdx.x * 256 + threadIdx.x;
  int h4 = (int)(idx & 255);
  int s  = (int)((idx >> 8) & 511);
  int b  = (int)(idx >> 17);
  const float4* src = (const float4*)in;
  float4 v = src[((size_t)b * SS + s) * 256 + h4];
  half4v hv = { (_Float16)v.x, (_Float16)v.y, (_Float16)v.z, (_Float16)v.w };
  *(half4v*)(x16 + ((size_t)s * BB + b) * HH + (size_t)h4 * 4) = hv;
}

// W[l][k][n] (f32) -> wT[m][n][k] (fp16); m: 0=Wx l0, 1=Wx l1, 2=Wh l0, 3=Wh l1
__global__ __launch_bounds__(256) void convert_w_kernel(const float* __restrict__ Wx,
                                                        const float* __restrict__ Wh,
                                                        _Float16* __restrict__ wT) {
  __shared__ float tile[32][33];
  int m = blockIdx.x >> 12;
  int t = blockIdx.x & 4095;
  int tn = t & 127, tk = t >> 7;
  int l = m & 1, which = m >> 1;
  const float* src = (which ? Wh : Wx) + (size_t)l * HH * G4;
  int tx = threadIdx.x & 31, ty = threadIdx.x >> 5;
#pragma unroll
  for (int p = 0; p < 4; ++p) {
    int k = tk * 32 + ty + 8 * p, n = tn * 32 + tx;
    tile[ty + 8 * p][tx] = src[(size_t)k * G4 + n];
  }
  __syncthreads();
  _Float16* dst = wT + (size_t)m * G4 * HH;
#pragma unroll
  for (int p = 0; p < 4; ++p) {
    int n = tn * 32 + ty + 8 * p, k = tk * 32 + tx;
    dst[(size_t)n * HH + k] = (_Float16)tile[tx][ty + 8 * p];
  }
}

// LEAN persistent LSTM: 256 blocks x 512 threads, R5 compute skeleton with a
// minimum-hop zero-contention sync chain.
//  - Per-block DEDICATED go line (1 poller/line, no poll contention).
//  - Arrive: 16 lines x 8 blocks (cumulative, order-safe) -> lvl2 -> last
//    arriver fans out go=t+1 to all 256 lines of its chain (both layers read
//    L1's go for the Phase-A gate).
//  - Publish: wave 0 only; lane r computes row r x 8 cols, two 8B agent-scope
//    stores (write-through); wave-local vmcnt(0); lane 0 arrives. No
//    block-wide sync on the publish path.
//  - Trajectory h slots (freshness-by-construction, no acquire fences).
__global__ __launch_bounds__(512, 2) void lstm_lean(
    const _Float16* __restrict__ x16, const _Float16* __restrict__ wT,
    const float* __restrict__ bx, const float* __restrict__ bh,
    _Float16* __restrict__ h1buf, _Float16* __restrict__ h2buf,
    float* __restrict__ hmax, u32* __restrict__ bar) {
  __shared__ float part[8][32][72];  // [wave][col][row+pad] = 73,728 B
  __shared__ float red[64][37];      // [row][nl+pad]        =  9,472 B

  const int bid = blockIdx.x;
  const int layer = bid >> 7;
  const int j = bid & 127;           // h-cols [8j, 8j+8)
  const int tid = threadIdx.x;
  const int w = tid >> 6, l = tid & 63;
  const int l15 = l & 15, lg = l >> 4;
  const int arline = (bid & 127) >> 3;  // 16 arrive lines per chain, 8 blocks each

  // ---- one-time: weight fragments into registers ----
  const _Float16* wTe = wT + (size_t)layer * G4 * HH;        // Wx of this layer
  const _Float16* wTr = wT + (size_t)(2 + layer) * G4 * HH;  // Wh of this layer
  const int kbase = w * 128;
  half8 Be[8], Br[8];
#pragma unroll
  for (int kk = 0; kk < 4; ++kk)
#pragma unroll
    for (int c = 0; c < 2; ++c) {
      int nl = 16 * c + l15;
      size_t gcol = (size_t)((nl & 3) * HH + 8 * j + (nl >> 2));
      Be[kk * 2 + c] = *(const half8*)(wTe + gcol * HH + kbase + 32 * kk + 8 * lg);
      Br[kk * 2 + c] = *(const half8*)(wTr + gcol * HH + kbase + 32 * kk + 8 * lg);
    }

  // ---- wave-0 epilogue state: lane r owns row r, 8 cols [8j..8j+8) ----
  float bsv[32];   // [cp*4+gate]
  float cst[8], hx[8];
#pragma unroll
  for (int cp = 0; cp < 8; ++cp) {
    cst[cp] = 0.f;
    hx[cp] = -2.f;
#pragma unroll
    for (int g = 0; g < 4; ++g)
      bsv[cp * 4 + g] = bx[layer * G4 + g * HH + 8 * j + cp] + bh[layer * G4 + g * HH + 8 * j + cp];
  }

#pragma unroll 1
  for (int t = 0; t < NSTEP; ++t) {
    const bool act = (layer == 0) ? (t < SS) : (t >= 2);
    f32x4 acc[8];
#pragma unroll
    for (int i = 0; i < 8; ++i) acc[i] = (f32x4){0.f, 0.f, 0.f, 0.f};

    // ---- Phase A gate (L2 only): h1 slot t-1 written once go0 >= t-1 ----
    if (layer == 1) {
      if (tid == 0 && t >= 2) wait_ge(bar + GOD(0, bid), (u32)(t - 1));
      __builtin_amdgcn_s_barrier();
      asm volatile("" ::: "memory");
    }

    // ---- Phase A: input-half (off-chain). L1: x_t @ Wx1. L2: h1[t-2] @ Wx2.
    if (act) {
      const _Float16* Ae = (layer == 0) ? x16 + (size_t)t * SLOT
                                        : h1buf + (size_t)(t - 1) * SLOT;
      const _Float16* aep = Ae + (size_t)l15 * HH + kbase + 8 * lg;
      half8 a[16];
#pragma unroll
      for (int rf = 0; rf < 4; ++rf)
#pragma unroll
        for (int kk = 0; kk < 4; ++kk)
          a[rf * 4 + kk] = *(const half8*)(aep + (size_t)(16 * rf) * HH + 32 * kk);
#pragma unroll
      for (int rf = 0; rf < 4; ++rf)
#pragma unroll
        for (int kk = 0; kk < 4; ++kk) {
          acc[rf * 2 + 0] = __builtin_amdgcn_mfma_f32_16x16x32_f16(a[rf * 4 + kk], Be[kk * 2 + 0], acc[rf * 2 + 0], 0, 0, 0);
          acc[rf * 2 + 1] = __builtin_amdgcn_mfma_f32_16x16x32_f16(a[rf * 4 + kk], Be[kk * 2 + 1], acc[rf * 2 + 1], 0, 0, 0);
        }
    }

    // ---- Phase B: wait own chain release(t-1) on DEDICATED line ----
    if (tid == 0) wait_ge(bar + GOD(layer, bid), (u32)t);
    __builtin_amdgcn_s_barrier();
    asm volatile("" ::: "memory");

    // ---- Phase C: recurrent half (on-chain). L1: h1[t-1]=slot t. L2: h2[t-3]=slot t-2.
    if (act) {
      const _Float16* Ah = (layer == 0) ? h1buf + (size_t)t * SLOT
                                        : h2buf + (size_t)(t - 2) * SLOT;
      const _Float16* ahp = Ah + (size_t)l15 * HH + kbase + 8 * lg;
      half8 a[16];
#pragma unroll
      for (int rf = 0; rf < 4; ++rf)
#pragma unroll
        for (int kk = 0; kk < 4; ++kk)
          a[rf * 4 + kk] = *(const half8*)(ahp + (size_t)(16 * rf) * HH + 32 * kk);
#pragma unroll
      for (int rf = 0; rf < 4; ++rf)
#pragma unroll
        for (int kk = 0; kk < 4; ++kk) {
          acc[rf * 2 + 0] = __builtin_amdgcn_mfma_f32_16x16x32_f16(a[rf * 4 + kk], Br[kk * 2 + 0], acc[rf * 2 + 0], 0, 0, 0);
          acc[rf * 2 + 1] = __builtin_amdgcn_mfma_f32_16x16x32_f16(a[rf * 4 + kk], Br[kk * 2 + 1], acc[rf * 2 + 1], 0, 0, 0);
        }

#pragma unroll
      for (int rf = 0; rf < 4; ++rf)
#pragma unroll
        for (int c = 0; c < 2; ++c)
          *(f32x4*)&part[w][16 * c + l15][16 * rf + 4 * lg] = acc[rf * 2 + c];
      __syncthreads();

      {  // gather across waves -> red[row][nl]
        int col = tid >> 4, rq = tid & 15;
        f32x4 s = {0.f, 0.f, 0.f, 0.f};
#pragma unroll
        for (int ww = 0; ww < 8; ++ww)
          s += *(const f32x4*)&part[ww][col][4 * rq];
        red[4 * rq + 0][col] = s[0];
        red[4 * rq + 1][col] = s[1];
        red[4 * rq + 2][col] = s[2];
        red[4 * rq + 3][col] = s[3];
      }
      __syncthreads();

      // ---- wave-0 epilogue: lane r = row r, all 8 cols; two 8B publishes ----
      if (w == 0) {
        u32 pk[4];
#pragma unroll
        for (int cp = 0; cp < 8; ++cp) {
          float vi = red[l][4 * cp + 0] + bsv[cp * 4 + 0];
          float vf = red[l][4 * cp + 1] + bsv[cp * 4 + 1];
          float vg = red[l][4 * cp + 2] + bsv[cp * 4 + 2];
          float vo = red[l][4 * cp + 3] + bsv[cp * 4 + 3];
          float ig = sigmf(vi), fg = sigmf(vf), gg = tanhfast(vg), og = sigmf(vo);
          float cn = fg * cst[cp] + ig * gg;
          cst[cp] = cn;
          float hn = tanhfast(cn) * og;
          if (layer == 1) hx[cp] = fmaxf(hx[cp], hn);
          u32 hb = (u32)__builtin_bit_cast(unsigned short, (_Float16)hn);
          if ((cp & 1) == 0) pk[cp >> 1] = hb;
          else pk[cp >> 1] |= hb << 16;
        }
        _Float16* hout = (layer == 0) ? h1buf + (size_t)(t + 1) * SLOT
                                      : h2buf + (size_t)(t - 1) * SLOT;
        u64* dst = (u64*)(hout + (size_t)l * HH + 8 * j);
        astore64(dst,     ((u64)pk[1] << 32) | pk[0]);
        astore64(dst + 1, ((u64)pk[3] << 32) | pk[2]);
        asm volatile("s_waitcnt vmcnt(0)" ::: "memory");  // wave-local drain
      }
    }

    // ---- arrive + release (lane 0 of wave 0; publish already drained) ----
    if (tid == 0) {
      u32 prev = aadd(bar + ARRD(layer, arline));
      if (prev == 8u * (u32)(t + 1) - 1u) {
        u32 p2 = aadd(bar + LVL2D(layer));
        if (p2 == 16u * (u32)(t + 1) - 1u) {
#pragma unroll 4
          for (int b = 0; b < 256; ++b)
            astore(bar + GOD(layer, b), (u32)(t + 1));
        }
      }
    }
  }

  if (layer == 1 && w == 0) {
    float* hp = hmax + (size_t)l * HH + 8 * j;
    *(float4*)hp = (float4){hx[0], hx[1], hx[2], hx[3]};
    *(float4*)(hp + 4) = (float4){hx[4], hx[5], hx[6], hx[7]};
  }
}

// SAFE fallback (round-5 proven, 256 blocks, rings + per-step acquire fence).
__global__ __launch_bounds__(512, 2) void lstm_safe(
    const _Float16* __restrict__ x16, const _Float16* __restrict__ wT,
    const float* __restrict__ bx, const float* __restrict__ bh,
    _Float16* __restrict__ h1buf, _Float16* __restrict__ h2buf,
    float* __restrict__ hmax, u32* __restrict__ bar) {
  __shared__ float part[8][32][72];
  __shared__ float red[64][37];

  const int bid = blockIdx.x;
  const int layer = bid >> 7;
  const int j = bid & 127;
  const int tid = threadIdx.x;
  const int w = tid >> 6, l = tid & 63;
  const int l15 = l & 15, lg = l >> 4;
  const int grp = bid & 7;

  const _Float16* wTe = wT + (size_t)layer * G4 * HH;
  const _Float16* wTr = wT + (size_t)(2 + layer) * G4 * HH;
  const int kbase = w * 128;
  half8 Be[8], Br[8];
#pragma unroll
  for (int kk = 0; kk < 4; ++kk)
#pragma unroll
    for (int c = 0; c < 2; ++c) {
      int nl = 16 * c + l15;
      size_t gcol = (size_t)((nl & 3) * HH + 8 * j + (nl >> 2));
      Be[kk * 2 + c] = *(const half8*)(wTe + gcol * HH + kbase + 32 * kk + 8 * lg);
      Br[kk * 2 + c] = *(const half8*)(wTr + gcol * HH + kbase + 32 * kk + 8 * lg);
    }

  const int erow = tid >> 2, m2 = tid & 3;
  const int hc0 = 8 * j + 2 * m2;
  float bs[8];
  float c0 = 0.f, c1 = 0.f, hm0 = -2.f, hm1 = -2.f;
  if (tid < 256) {
#pragma unroll
    for (int dm = 0; dm < 2; ++dm)
#pragma unroll
      for (int g = 0; g < 4; ++g)
        bs[4 * dm + g] = bx[layer * G4 + g * HH + hc0 + dm] + bh[layer * G4 + g * HH + hc0 + dm];
  }

#pragma unroll 1
  for (int t = 0; t < NSTEP; ++t) {
    const bool act = (layer == 0) ? (t < SS) : (t >= 2);
    f32x4 acc[8];
#pragma unroll
    for (int i = 0; i < 8; ++i) acc[i] = (f32x4){0.f, 0.f, 0.f, 0.f};

    if (act) {
      const _Float16* Ae = (layer == 0) ? x16 + (size_t)t * SLOT
                                        : h1buf + (size_t)((t - 2) & 3) * SLOT;
      const _Float16* aep = Ae + (size_t)l15 * HH + kbase + 8 * lg;
      half8 a[16];
#pragma unroll
      for (int rf = 0; rf < 4; ++rf)
#pragma unroll
        for (int kk = 0; kk < 4; ++kk)
          a[rf * 4 + kk] = *(const half8*)(aep + (size_t)(16 * rf) * HH + 32 * kk);
#pragma unroll
      for (int rf = 0; rf < 4; ++rf)
#pragma unroll
        for (int kk = 0; kk < 4; ++kk) {
          acc[rf * 2 + 0] = __builtin_amdgcn_mfma_f32_16x16x32_f16(a[rf * 4 + kk], Be[kk * 2 + 0], acc[rf * 2 + 0], 0, 0, 0);
          acc[rf * 2 + 1] = __builtin_amdgcn_mfma_f32_16x16x32_f16(a[rf * 4 + kk], Be[kk * 2 + 1], acc[rf * 2 + 1], 0, 0, 0);
        }
    }

    if (tid == 0) {
      wait_ge(bar + SB_GO(grp), (u32)t);
      __builtin_amdgcn_fence(__ATOMIC_ACQUIRE, "agent");
    }
    __syncthreads();

    if (act) {
      const _Float16* Ah = (layer == 0) ? h1buf + (size_t)((t - 1) & 3) * SLOT
                                        : h2buf + (size_t)((t - 1) & 1) * SLOT;
      const _Float16* ahp = Ah + (size_t)l15 * HH + kbase + 8 * lg;
      half8 a[16];
#pragma unroll
      for (int rf = 0; rf < 4; ++rf)
#pragma unroll
        for (int kk = 0; kk < 4; ++kk)
          a[rf * 4 + kk] = *(const half8*)(ahp + (size_t)(16 * rf) * HH + 32 * kk);
#pragma unroll
      for (int rf = 0; rf < 4; ++rf)
#pragma unroll
        for (int kk = 0; kk < 4; ++kk) {
          acc[rf * 2 + 0] = __builtin_amdgcn_mfma_f32_16x16x32_f16(a[rf * 4 + kk], Br[kk * 2 + 0], acc[rf * 2 + 0], 0, 0, 0);
          acc[rf * 2 + 1] = __builtin_amdgcn_mfma_f32_16x16x32_f16(a[rf * 4 + kk], Br[kk * 2 + 1], acc[rf * 2 + 1], 0, 0, 0);
        }

#pragma unroll
      for (int rf = 0; rf < 4; ++rf)
#pragma unroll
        for (int c = 0; c < 2; ++c)
          *(f32x4*)&part[w][16 * c + l15][16 * rf + 4 * lg] = acc[rf * 2 + c];
      __syncthreads();

      {
        int col = tid >> 4, rq = tid & 15;
        f32x4 s = {0.f, 0.f, 0.f, 0.f};
#pragma unroll
        for (int ww = 0; ww < 8; ++ww)
          s += *(const f32x4*)&part[ww][col][4 * rq];
        red[4 * rq + 0][col] = s[0];
        red[4 * rq + 1][col] = s[1];
        red[4 * rq + 2][col] = s[2];
        red[4 * rq + 3][col] = s[3];
      }
      __syncthreads();

      if (tid < 256) {
        float v[8];
#pragma unroll
        for (int q = 0; q < 8; ++q) v[q] = red[erow][8 * m2 + q] + bs[q];
        float i0 = sigmf(v[0]), f0 = sigmf(v[1]), g0 = tanhfast(v[2]), o0 = sigmf(v[3]);
        float i1 = sigmf(v[4]), f1 = sigmf(v[5]), g1 = tanhfast(v[6]), o1 = sigmf(v[7]);
        c0 = f0 * c0 + i0 * g0;
        c1 = f1 * c1 + i1 * g1;
        float h0 = tanhfast(c0) * o0;
        float h1 = tanhfast(c1) * o1;
        if (layer == 1) { hm0 = fmaxf(hm0, h0); hm1 = fmaxf(hm1, h1); }
        _Float16* hout = (layer == 0) ? h1buf + (size_t)(t & 3) * SLOT
                                      : h2buf + (size_t)(t & 1) * SLOT;
        u32 pk = ((u32)__builtin_bit_cast(unsigned short, (_Float16)h1) << 16) |
                 (u32)__builtin_bit_cast(unsigned short, (_Float16)h0);
        astore((u32*)hout + ((erow * HH + hc0) >> 1), pk);
      }
    }

    __syncthreads();
    if (tid == 0) {
      u32 prev = aadd(bar + SB_ARR(grp));
      if (prev == 32u * (u32)(t + 1) - 1u) {
        u32 p2 = aadd(bar + SB_GLB);
        if (p2 == 8u * (u32)(t + 1) - 1u) {
#pragma unroll
          for (int gg = 0; gg < 8; ++gg)
            astore(bar + SB_GO(gg), (u32)(t + 1));
        }
      }
    }
  }

  if (layer == 1 && tid < 256) {
    hmax[erow * HH + hc0]     = hm0;
    hmax[erow * HH + hc0 + 1] = hm1;
  }
}

__global__ __launch_bounds__(320) void classify_kernel(const float* __restrict__ hmax,
                                                       const float* __restrict__ Wp,
                                                       const float* __restrict__ bp,
                                                       float* __restrict__ out) {
  int tid = threadIdx.x;  // 320 = 64*5
  int b = tid / 5, jj = tid % 5;
  float s = bp[jj];
  const float* hp = hmax + (size_t)b * HH;
  for (int h = 0; h < HH; ++h) s = fmaf(hp[h], Wp[h * 5 + jj], s);
  out[tid] = s;
}

extern "C" void kernel_launch(void* const* d_in, const int* in_sizes, int n_in,
                              void* d_out, int out_size, void* d_ws, size_t ws_size,
                              hipStream_t stream) {
  const float* inputs = (const float*)d_in[0];
  const float* Wx = (const float*)d_in[1];
  const float* bx = (const float*)d_in[2];
  const float* Wh = (const float*)d_in[3];
  const float* bh = (const float*)d_in[4];
  const float* Wp = (const float*)d_in[5];
  const float* bp = (const float*)d_in[6];
  float* out = (float*)d_out;

  char* ws = (char*)d_ws;
  _Float16* x16 = (_Float16*)(ws + 0);          // 67,108,864
  _Float16* wT  = (_Float16*)(ws + 67108864);   // 33,554,432 -> 100,663,296

  const size_t TRAJ_BYTES = (size_t)513 * 131072;  // 67,239,936
  const size_t BAR_BYTES = 40960;                  // 9216 dwords used
  const size_t NEED_FAST = 100663296ull + 2 * TRAJ_BYTES + 262144 + BAR_BYTES;
  bool fast = ws_size >= NEED_FAST;

  convert_x_kernel<<<32768, 256, 0, stream>>>(inputs, x16);
  convert_w_kernel<<<16384, 256, 0, stream>>>(Wx, Wh, wT);

  if (fast) {
    _Float16* h1traj = (_Float16*)(ws + 100663296);
    _Float16* h2traj = (_Float16*)(ws + 100663296 + TRAJ_BYTES);
    float* hmax = (float*)(ws + 100663296 + 2 * TRAJ_BYTES);
    u32* bar = (u32*)(ws + 100663296 + 2 * TRAJ_BYTES + 262144);
    hipMemsetAsync(h1traj, 0, 131072, stream);  // slot 0 = state at t-1 (zeros)
    hipMemsetAsync(h2traj, 0, 131072, stream);
    hipMemsetAsync(bar, 0, BAR_BYTES, stream);
    lstm_lean<<<256, 512, 0, stream>>>(x16, wT, bx, bh, h1traj, h2traj, hmax, bar);
    classify_kernel<<<1, 320, 0, stream>>>(hmax, Wp, bp, out);
  } else {
    _Float16* h1buf = (_Float16*)(ws + 100663296);  // 4 slots
    _Float16* h2buf = (_Float16*)(ws + 101187584);  // 2 slots
    float* hmax = (float*)(ws + 101449728);
    u32* bar = (u32*)(ws + 101711872);
    hipMemsetAsync(h1buf, 0, 524288, stream);
    hipMemsetAsync(h2buf, 0, 262144, stream);
    hipMemsetAsync(bar, 0, 8192, stream);
    lstm_safe<<<256, 512, 0, stream>>>(x16, wT, bx, bh, h1buf, h2buf, hmax, bar);
    classify_kernel<<<1, 320, 0, stream>>>(hmax, Wp, bp, out);
  }
}

// Round 13
// 4305.951 us; speedup vs baseline: 1.8605x; 1.4983x over previous
//
#include <hip/hip_runtime.h>
#include <hip/hip_bf16.h>

typedef _Float16 half8 __attribute__((ext_vector_type(8)));
typedef _Float16 half4v __attribute__((ext_vector_type(4)));
typedef float f32x4 __attribute__((ext_vector_type(4)));
typedef unsigned int u32;
typedef unsigned long long u64;

#define BB 64
#define SS 512
#define HH 1024
#define G4 4096
#define SLOT 65536   // elements per 64x1024 fp16 h-slot

// SAFE-mode (R5 fallback) barrier words
#define SB_ARR(g) ((g) * 32)
#define SB_GLB 256
#define SB_GO(g) (288 + (g) * 32)
#define NSTEP 514

__device__ __forceinline__ float sigmf(float x) { return 1.0f / (1.0f + __expf(-x)); }
__device__ __forceinline__ float tanhfast(float x) { return 2.0f / (1.0f + __expf(-2.0f * x)) - 1.0f; }

__device__ __forceinline__ u32 aload(const u32* p) {
  return __hip_atomic_load(p, __ATOMIC_RELAXED, __HIP_MEMORY_SCOPE_AGENT);
}
__device__ __forceinline__ void wait_ge(const u32* p, u32 tgt) {
  while (aload(p) < tgt) __builtin_amdgcn_s_sleep(1);
}
__device__ __forceinline__ u32 aadd(u32* p) {
  return __hip_atomic_fetch_add(p, 1u, __ATOMIC_RELAXED, __HIP_MEMORY_SCOPE_AGENT);
}
__device__ __forceinline__ void astore(u32* p, u32 v) {
  __hip_atomic_store(p, v, __ATOMIC_RELAXED, __HIP_MEMORY_SCOPE_AGENT);
}
__device__ __forceinline__ void astore64(u64* p, u64 v) {
  __hip_atomic_store(p, v, __ATOMIC_RELAXED, __HIP_MEMORY_SCOPE_AGENT);
}

// inputs[b][s][h] (f32) -> x16[s][b][h] (fp16), time-major
__global__ __launch_bounds__(256) void convert_x_kernel(const float* __restrict__ in,
                                                        _Float16* __restrict__ x16) {
  size_t idx = (size_t)blockIdx.x * 256 + threadIdx.x;
  int h4 = (int)(idx & 255);
  int s  = (int)((idx >> 8) & 511);
  int b  = (int)(idx >> 17);
  const float4* src = (const float4*)in;
  float4 v = src[((size_t)b * SS + s) * 256 + h4];
  half4v hv = { (_Float16)v.x, (_Float16)v.y, (_Float16)v.z, (_Float16)v.w };
  *(half4v*)(x16 + ((size_t)s * BB + b) * HH + (size_t)h4 * 4) = hv;
}

// W[l][k][n] (f32) -> wT[m][n][k] (fp16); m: 0=Wx l0, 1=Wx l1, 2=Wh l0, 3=Wh l1
__global__ __launch_bounds__(256) void convert_w_kernel(const float* __restrict__ Wx,
                                                        const float* __restrict__ Wh,
                                                        _Float16* __restrict__ wT) {
  __shared__ float tile[32][33];
  int m = blockIdx.x >> 12;
  int t = blockIdx.x & 4095;
  int tn = t & 127, tk = t >> 7;
  int l = m & 1, which = m >> 1;
  const float* src = (which ? Wh : Wx) + (size_t)l * HH * G4;
  int tx = threadIdx.x & 31, ty = threadIdx.x >> 5;
#pragma unroll
  for (int p = 0; p < 4; ++p) {
    int k = tk * 32 + ty + 8 * p, n = tn * 32 + tx;
    tile[ty + 8 * p][tx] = src[(size_t)k * G4 + n];
  }
  __syncthreads();
  _Float16* dst = wT + (size_t)m * G4 * HH;
#pragma unroll
  for (int p = 0; p < 4; ++p) {
    int n = tn * 32 + ty + 8 * p, k = tk * 32 + tx;
    dst[(size_t)n * HH + k] = (_Float16)tile[tx][ty + 8 * p];
  }
}

// FLOW persistent LSTM: pure producer->consumer dataflow, NO barriers.
// 256 blocks x 512 threads (1 block/CU via 83KB LDS). Blocks 0..127: L1 step
// t=0..511; blocks 128..255: L2 step u=0..511 (free-running, decoupled).
// h trajectories (write-once slots) + per-(slot, producer-tile) tags:
//   tag[t][rep][j] = 1 once h slot t tile j (8 cols) is at the coherence point
//   (producer: data stores -> wave-local vmcnt(0) -> tag store).
// Consumer wave w needs only tiles j in [16w,16w+16): its 16 lanes poll those
// tag words (agent-scope loads, one L3 RTT, __all vote), then read the slice
// normally (compulsory L2 miss on the fresh slot -> L3-fresh data; R5-proven).
// Chain/step = drain + tag store + poll + read: ~2 visibility hops, no RMWs,
// no collective rendezvous, no inter-layer lockstep, no deadlock cycles.
__global__ __launch_bounds__(512, 2) void lstm_flow(
    const _Float16* __restrict__ x16, const _Float16* __restrict__ wT,
    const float* __restrict__ bx, const float* __restrict__ bh,
    _Float16* __restrict__ h1buf, _Float16* __restrict__ h2buf,
    float* __restrict__ hmax, u32* __restrict__ tag1, u32* __restrict__ tag2) {
  __shared__ float part[8][32][72];  // [wave][col][row+pad] = 73,728 B
  __shared__ float red[64][37];      // [row][nl+pad]        =  9,472 B

  const int bid = blockIdx.x;
  const int layer = bid >> 7;
  const int j = bid & 127;           // h-cols [8j, 8j+8)
  const int tid = threadIdx.x;
  const int w = tid >> 6, l = tid & 63;
  const int l15 = l & 15, lg = l >> 4;
  const int rep = bid & 1;

  // ---- one-time: weight fragments into registers ----
  const _Float16* wTe = wT + (size_t)layer * G4 * HH;        // Wx of this layer
  const _Float16* wTr = wT + (size_t)(2 + layer) * G4 * HH;  // Wh of this layer
  const int kbase = w * 128;
  half8 Be[8], Br[8];
#pragma unroll
  for (int kk = 0; kk < 4; ++kk)
#pragma unroll
    for (int c = 0; c < 2; ++c) {
      int nl = 16 * c + l15;
      size_t gcol = (size_t)((nl & 3) * HH + 8 * j + (nl >> 2));
      Be[kk * 2 + c] = *(const half8*)(wTe + gcol * HH + kbase + 32 * kk + 8 * lg);
      Br[kk * 2 + c] = *(const half8*)(wTr + gcol * HH + kbase + 32 * kk + 8 * lg);
    }

  // ---- wave-0 epilogue state: lane r owns row r, 8 cols [8j..8j+8) ----
  float bsv[32];  // [cp*4+gate]
  float cst[8], hx[8];
#pragma unroll
  for (int cp = 0; cp < 8; ++cp) {
    cst[cp] = 0.f;
    hx[cp] = -2.f;
#pragma unroll
    for (int g = 0; g < 4; ++g)
      bsv[cp * 4 + g] = bx[layer * G4 + g * HH + 8 * j + cp] + bh[layer * G4 + g * HH + 8 * j + cp];
  }

  // wave-level poll: lane i<16 polls tag row word 16w+i until all nonzero
#define POLL(TAGS, SLOTT)                                                              \
  {                                                                                    \
    const u32* tp = (TAGS) + ((size_t)(SLOTT) * 2 + rep) * 128 + 16 * w + l15;         \
    while (true) {                                                                     \
      u32 v = (l < 16) ? aload(tp) : 1u;                                               \
      if (__all(v != 0)) break;                                                        \
      __builtin_amdgcn_s_sleep(2);                                                     \
    }                                                                                  \
    asm volatile("" ::: "memory");                                                     \
  }

#pragma unroll 1
  for (int t = 0; t < SS; ++t) {
    f32x4 acc[8];
#pragma unroll
    for (int i = 0; i < 8; ++i) acc[i] = (f32x4){0.f, 0.f, 0.f, 0.f};

    // ---- Phase A: input-half. L1: x_t (static). L2: h1[t] = slot t+1 (tag-gated).
    {
      const _Float16* Ae;
      if (layer == 0) {
        Ae = x16 + (size_t)t * SLOT;
      } else {
        POLL(tag1, t + 1)
        Ae = h1buf + (size_t)(t + 1) * SLOT;
      }
      const _Float16* aep = Ae + (size_t)l15 * HH + kbase + 8 * lg;
      half8 a[16];
#pragma unroll
      for (int rf = 0; rf < 4; ++rf)
#pragma unroll
        for (int kk = 0; kk < 4; ++kk)
          a[rf * 4 + kk] = *(const half8*)(aep + (size_t)(16 * rf) * HH + 32 * kk);
#pragma unroll
      for (int rf = 0; rf < 4; ++rf)
#pragma unroll
        for (int kk = 0; kk < 4; ++kk) {
          acc[rf * 2 + 0] = __builtin_amdgcn_mfma_f32_16x16x32_f16(a[rf * 4 + kk], Be[kk * 2 + 0], acc[rf * 2 + 0], 0, 0, 0);
          acc[rf * 2 + 1] = __builtin_amdgcn_mfma_f32_16x16x32_f16(a[rf * 4 + kk], Be[kk * 2 + 1], acc[rf * 2 + 1], 0, 0, 0);
        }
    }

    // ---- Phase C: recurrent half. h[t-1] = slot t (tag-gated for t>=1).
    {
      const _Float16* Ah;
      if (layer == 0) {
        if (t >= 1) POLL(tag1, t)
        Ah = h1buf + (size_t)t * SLOT;
      } else {
        if (t >= 1) POLL(tag2, t)
        Ah = h2buf + (size_t)t * SLOT;
      }
      const _Float16* ahp = Ah + (size_t)l15 * HH + kbase + 8 * lg;
      half8 a[16];
#pragma unroll
      for (int rf = 0; rf < 4; ++rf)
#pragma unroll
        for (int kk = 0; kk < 4; ++kk)
          a[rf * 4 + kk] = *(const half8*)(ahp + (size_t)(16 * rf) * HH + 32 * kk);
#pragma unroll
      for (int rf = 0; rf < 4; ++rf)
#pragma unroll
        for (int kk = 0; kk < 4; ++kk) {
          acc[rf * 2 + 0] = __builtin_amdgcn_mfma_f32_16x16x32_f16(a[rf * 4 + kk], Br[kk * 2 + 0], acc[rf * 2 + 0], 0, 0, 0);
          acc[rf * 2 + 1] = __builtin_amdgcn_mfma_f32_16x16x32_f16(a[rf * 4 + kk], Br[kk * 2 + 1], acc[rf * 2 + 1], 0, 0, 0);
        }
    }

    // ---- K-reduction through LDS ----
#pragma unroll
    for (int rf = 0; rf < 4; ++rf)
#pragma unroll
      for (int c = 0; c < 2; ++c)
        *(f32x4*)&part[w][16 * c + l15][16 * rf + 4 * lg] = acc[rf * 2 + c];
    __syncthreads();

    {  // gather across waves -> red[row][nl]
      int col = tid >> 4, rq = tid & 15;
      f32x4 s = {0.f, 0.f, 0.f, 0.f};
#pragma unroll
      for (int ww = 0; ww < 8; ++ww)
        s += *(const f32x4*)&part[ww][col][4 * rq];
      red[4 * rq + 0][col] = s[0];
      red[4 * rq + 1][col] = s[1];
      red[4 * rq + 2][col] = s[2];
      red[4 * rq + 3][col] = s[3];
    }
    __syncthreads();

    // ---- wave-0 epilogue + publish + tag ----
    if (w == 0) {
      u32 pk[4];
#pragma unroll
      for (int cp = 0; cp < 8; ++cp) {
        float vi = red[l][4 * cp + 0] + bsv[cp * 4 + 0];
        float vf = red[l][4 * cp + 1] + bsv[cp * 4 + 1];
        float vg = red[l][4 * cp + 2] + bsv[cp * 4 + 2];
        float vo = red[l][4 * cp + 3] + bsv[cp * 4 + 3];
        float ig = sigmf(vi), fg = sigmf(vf), gg = tanhfast(vg), og = sigmf(vo);
        float cn = fg * cst[cp] + ig * gg;
        cst[cp] = cn;
        float hn = tanhfast(cn) * og;
        if (layer == 1) hx[cp] = fmaxf(hx[cp], hn);
        u32 hb = (u32)__builtin_bit_cast(unsigned short, (_Float16)hn);
        if ((cp & 1) == 0) pk[cp >> 1] = hb;
        else pk[cp >> 1] |= hb << 16;
      }
      if (layer == 0 || t < SS - 1) {  // L2's last h feeds only hmax (in regs)
        _Float16* hout = (layer == 0 ? h1buf : h2buf) + (size_t)(t + 1) * SLOT;
        u64* dst = (u64*)(hout + (size_t)l * HH + 8 * j);
        astore64(dst,     ((u64)pk[1] << 32) | pk[0]);
        astore64(dst + 1, ((u64)pk[3] << 32) | pk[2]);
        asm volatile("s_waitcnt vmcnt(0)" ::: "memory");  // data at coherence point
        if (l == 0) {
          u32* tg = (layer == 0 ? tag1 : tag2);
          astore(tg + ((size_t)(t + 1) * 2 + 0) * 128 + j, 1u);
          astore(tg + ((size_t)(t + 1) * 2 + 1) * 128 + j, 1u);
        }
      }
    }
  }
#undef POLL

  if (layer == 1 && w == 0) {
    float* hp = hmax + (size_t)l * HH + 8 * j;
    *(float4*)hp = (float4){hx[0], hx[1], hx[2], hx[3]};
    *(float4*)(hp + 4) = (float4){hx[4], hx[5], hx[6], hx[7]};
  }
}

// SAFE fallback (round-5 proven, 256 blocks, rings + per-step acquire fence).
__global__ __launch_bounds__(512, 2) void lstm_safe(
    const _Float16* __restrict__ x16, const _Float16* __restrict__ wT,
    const float* __restrict__ bx, const float* __restrict__ bh,
    _Float16* __restrict__ h1buf, _Float16* __restrict__ h2buf,
    float* __restrict__ hmax, u32* __restrict__ bar) {
  __shared__ float part[8][32][72];
  __shared__ float red[64][37];

  const int bid = blockIdx.x;
  const int layer = bid >> 7;
  const int j = bid & 127;
  const int tid = threadIdx.x;
  const int w = tid >> 6, l = tid & 63;
  const int l15 = l & 15, lg = l >> 4;
  const int grp = bid & 7;

  const _Float16* wTe = wT + (size_t)layer * G4 * HH;
  const _Float16* wTr = wT + (size_t)(2 + layer) * G4 * HH;
  const int kbase = w * 128;
  half8 Be[8], Br[8];
#pragma unroll
  for (int kk = 0; kk < 4; ++kk)
#pragma unroll
    for (int c = 0; c < 2; ++c) {
      int nl = 16 * c + l15;
      size_t gcol = (size_t)((nl & 3) * HH + 8 * j + (nl >> 2));
      Be[kk * 2 + c] = *(const half8*)(wTe + gcol * HH + kbase + 32 * kk + 8 * lg);
      Br[kk * 2 + c] = *(const half8*)(wTr + gcol * HH + kbase + 32 * kk + 8 * lg);
    }

  const int erow = tid >> 2, m2 = tid & 3;
  const int hc0 = 8 * j + 2 * m2;
  float bs[8];
  float c0 = 0.f, c1 = 0.f, hm0 = -2.f, hm1 = -2.f;
  if (tid < 256) {
#pragma unroll
    for (int dm = 0; dm < 2; ++dm)
#pragma unroll
      for (int g = 0; g < 4; ++g)
        bs[4 * dm + g] = bx[layer * G4 + g * HH + hc0 + dm] + bh[layer * G4 + g * HH + hc0 + dm];
  }

#pragma unroll 1
  for (int t = 0; t < NSTEP; ++t) {
    const bool act = (layer == 0) ? (t < SS) : (t >= 2);
    f32x4 acc[8];
#pragma unroll
    for (int i = 0; i < 8; ++i) acc[i] = (f32x4){0.f, 0.f, 0.f, 0.f};

    if (act) {
      const _Float16* Ae = (layer == 0) ? x16 + (size_t)t * SLOT
                                        : h1buf + (size_t)((t - 2) & 3) * SLOT;
      const _Float16* aep = Ae + (size_t)l15 * HH + kbase + 8 * lg;
      half8 a[16];
#pragma unroll
      for (int rf = 0; rf < 4; ++rf)
#pragma unroll
        for (int kk = 0; kk < 4; ++kk)
          a[rf * 4 + kk] = *(const half8*)(aep + (size_t)(16 * rf) * HH + 32 * kk);
#pragma unroll
      for (int rf = 0; rf < 4; ++rf)
#pragma unroll
        for (int kk = 0; kk < 4; ++kk) {
          acc[rf * 2 + 0] = __builtin_amdgcn_mfma_f32_16x16x32_f16(a[rf * 4 + kk], Be[kk * 2 + 0], acc[rf * 2 + 0], 0, 0, 0);
          acc[rf * 2 + 1] = __builtin_amdgcn_mfma_f32_16x16x32_f16(a[rf * 4 + kk], Be[kk * 2 + 1], acc[rf * 2 + 1], 0, 0, 0);
        }
    }

    if (tid == 0) {
      wait_ge(bar + SB_GO(grp), (u32)t);
      __builtin_amdgcn_fence(__ATOMIC_ACQUIRE, "agent");
    }
    __syncthreads();

    if (act) {
      const _Float16* Ah = (layer == 0) ? h1buf + (size_t)((t - 1) & 3) * SLOT
                                        : h2buf + (size_t)((t - 1) & 1) * SLOT;
      const _Float16* ahp = Ah + (size_t)l15 * HH + kbase + 8 * lg;
      half8 a[16];
#pragma unroll
      for (int rf = 0; rf < 4; ++rf)
#pragma unroll
        for (int kk = 0; kk < 4; ++kk)
          a[rf * 4 + kk] = *(const half8*)(ahp + (size_t)(16 * rf) * HH + 32 * kk);
#pragma unroll
      for (int rf = 0; rf < 4; ++rf)
#pragma unroll
        for (int kk = 0; kk < 4; ++kk) {
          acc[rf * 2 + 0] = __builtin_amdgcn_mfma_f32_16x16x32_f16(a[rf * 4 + kk], Br[kk * 2 + 0], acc[rf * 2 + 0], 0, 0, 0);
          acc[rf * 2 + 1] = __builtin_amdgcn_mfma_f32_16x16x32_f16(a[rf * 4 + kk], Br[kk * 2 + 1], acc[rf * 2 + 1], 0, 0, 0);
        }

#pragma unroll
      for (int rf = 0; rf < 4; ++rf)
#pragma unroll
        for (int c = 0; c < 2; ++c)
          *(f32x4*)&part[w][16 * c + l15][16 * rf + 4 * lg] = acc[rf * 2 + c];
      __syncthreads();

      {
        int col = tid >> 4, rq = tid & 15;
        f32x4 s = {0.f, 0.f, 0.f, 0.f};
#pragma unroll
        for (int ww = 0; ww < 8; ++ww)
          s += *(const f32x4*)&part[ww][col][4 * rq];
        red[4 * rq + 0][col] = s[0];
        red[4 * rq + 1][col] = s[1];
        red[4 * rq + 2][col] = s[2];
        red[4 * rq + 3][col] = s[3];
      }
      __syncthreads();

      if (tid < 256) {
        float v[8];
#pragma unroll
        for (int q = 0; q < 8; ++q) v[q] = red[erow][8 * m2 + q] + bs[q];
        float i0 = sigmf(v[0]), f0 = sigmf(v[1]), g0 = tanhfast(v[2]), o0 = sigmf(v[3]);
        float i1 = sigmf(v[4]), f1 = sigmf(v[5]), g1 = tanhfast(v[6]), o1 = sigmf(v[7]);
        c0 = f0 * c0 + i0 * g0;
        c1 = f1 * c1 + i1 * g1;
        float h0 = tanhfast(c0) * o0;
        float h1 = tanhfast(c1) * o1;
        if (layer == 1) { hm0 = fmaxf(hm0, h0); hm1 = fmaxf(hm1, h1); }
        _Float16* hout = (layer == 0) ? h1buf + (size_t)(t & 3) * SLOT
                                      : h2buf + (size_t)(t & 1) * SLOT;
        u32 pk = ((u32)__builtin_bit_cast(unsigned short, (_Float16)h1) << 16) |
                 (u32)__builtin_bit_cast(unsigned short, (_Float16)h0);
        astore((u32*)hout + ((erow * HH + hc0) >> 1), pk);
      }
    }

    __syncthreads();
    if (tid == 0) {
      u32 prev = aadd(bar + SB_ARR(grp));
      if (prev == 32u * (u32)(t + 1) - 1u) {
        u32 p2 = aadd(bar + SB_GLB);
        if (p2 == 8u * (u32)(t + 1) - 1u) {
#pragma unroll
          for (int gg = 0; gg < 8; ++gg)
            astore(bar + SB_GO(gg), (u32)(t + 1));
        }
      }
    }
  }

  if (layer == 1 && tid < 256) {
    hmax[erow * HH + hc0]     = hm0;
    hmax[erow * HH + hc0 + 1] = hm1;
  }
}

__global__ __launch_bounds__(320) void classify_kernel(const float* __restrict__ hmax,
                                                       const float* __restrict__ Wp,
                                                       const float* __restrict__ bp,
                                                       float* __restrict__ out) {
  int tid = threadIdx.x;  // 320 = 64*5
  int b = tid / 5, jj = tid % 5;
  float s = bp[jj];
  const float* hp = hmax + (size_t)b * HH;
  for (int h = 0; h < HH; ++h) s = fmaf(hp[h], Wp[h * 5 + jj], s);
  out[tid] = s;
}

extern "C" void kernel_launch(void* const* d_in, const int* in_sizes, int n_in,
                              void* d_out, int out_size, void* d_ws, size_t ws_size,
                              hipStream_t stream) {
  const float* inputs = (const float*)d_in[0];
  const float* Wx = (const float*)d_in[1];
  const float* bx = (const float*)d_in[2];
  const float* Wh = (const float*)d_in[3];
  const float* bh = (const float*)d_in[4];
  const float* Wp = (const float*)d_in[5];
  const float* bp = (const float*)d_in[6];
  float* out = (float*)d_out;

  char* ws = (char*)d_ws;
  _Float16* x16 = (_Float16*)(ws + 0);          // 67,108,864
  _Float16* wT  = (_Float16*)(ws + 67108864);   // 33,554,432 -> 100,663,296

  // FLOW layout
  const size_t H1_OFF = 100663296ull;
  const size_t H1_BYTES = (size_t)513 * 131072;       // 67,239,936
  const size_t H2_OFF = H1_OFF + H1_BYTES;            // 167,903,232
  const size_t H2_BYTES = (size_t)512 * 131072;       // 67,108,864
  const size_t HMAX_OFF = H2_OFF + H2_BYTES;          // 235,012,096
  const size_t TAG1_OFF = HMAX_OFF + 262144;          // 235,274,240
  const size_t TAG_BYTES = (size_t)513 * 2 * 128 * 4; // 525,312
  const size_t TAG2_OFF = TAG1_OFF + TAG_BYTES;       // 235,799,552
  const size_t NEED_FAST = TAG2_OFF + TAG_BYTES;      // 236,324,864
  bool fast = ws_size >= NEED_FAST;

  convert_x_kernel<<<32768, 256, 0, stream>>>(inputs, x16);
  convert_w_kernel<<<16384, 256, 0, stream>>>(Wx, Wh, wT);

  if (fast) {
    _Float16* h1traj = (_Float16*)(ws + H1_OFF);
    _Float16* h2traj = (_Float16*)(ws + H2_OFF);
    float* hmax = (float*)(ws + HMAX_OFF);
    u32* tag1 = (u32*)(ws + TAG1_OFF);
    u32* tag2 = (u32*)(ws + TAG2_OFF);
    hipMemsetAsync(h1traj, 0, 131072, stream);   // slot 0 = state at t=-1 (zeros)
    hipMemsetAsync(h2traj, 0, 131072, stream);
    hipMemsetAsync(tag1, 0, 2 * TAG_BYTES, stream);  // tag1+tag2 contiguous
    lstm_flow<<<256, 512, 0, stream>>>(x16, wT, bx, bh, h1traj, h2traj, hmax, tag1, tag2);
    classify_kernel<<<1, 320, 0, stream>>>(hmax, Wp, bp, out);
  } else {
    _Float16* h1buf = (_Float16*)(ws + 100663296);  // 4 slots
    _Float16* h2buf = (_Float16*)(ws + 101187584);  // 2 slots
    float* hmax = (float*)(ws + 101449728);
    u32* bar = (u32*)(ws + 101711872);
    hipMemsetAsync(h1buf, 0, 524288, stream);
    hipMemsetAsync(h2buf, 0, 262144, stream);
    hipMemsetAsync(bar, 0, 8192, stream);
    lstm_safe<<<256, 512, 0, stream>>>(x16, wT, bx, bh, h1buf, h2buf, hmax, bar);
    classify_kernel<<<1, 320, 0, stream>>>(hmax, Wp, bp, out);
  }
}